// Round 1
// baseline (2891.688 us; speedup 1.0000x reference)
//
#include <hip/hip_runtime.h>
#include <hip/hip_bf16.h>
#include <cstdint>

// ---------------------------------------------------------------------------
// SplineNet forward on gfx950.
// Pipeline:
//   1. CSR build: deg histogram -> block scan -> edge scatter (sorted by dst)
//   2. Per layer: acc_kernel (wave-per-node, T_n[25][32] in LDS via ds_add)
//                 -> chunked global T -> gemm_kernel [64 x COUT] tiles with
//                 fused /deg + root + bias + relu epilogue
//   3. pool_kernel (binary search over sorted batch) + head_kernel (gated MLP)
// ---------------------------------------------------------------------------

__device__ __forceinline__ int lowb(const int* __restrict__ a, int n, int v) {
  int lo = 0, hi = n;
  while (lo < hi) { int m = (lo + hi) >> 1; if (a[m] < v) lo = m + 1; else hi = m; }
  return lo;
}

__global__ void hist_kernel(const int* __restrict__ dst, int E, int* __restrict__ deg) {
  int e = blockIdx.x * 256 + threadIdx.x;
  if (e < E) atomicAdd(&deg[dst[e]], 1);
}

// Inclusive scan within blocks of 1024; writes offs[gi+1], block totals to bsums.
__global__ __launch_bounds__(1024) void scan_block_kernel(
    const int* __restrict__ deg, int n, int* __restrict__ offs, int* __restrict__ bsums) {
  __shared__ int wsum[16];
  int t = threadIdx.x;
  int gi = blockIdx.x * 1024 + t;
  int v = (gi < n) ? deg[gi] : 0;
  int lane = t & 63, w = t >> 6;
  int x = v;
  #pragma unroll
  for (int d = 1; d < 64; d <<= 1) { int y = __shfl_up(x, d, 64); if (lane >= d) x += y; }
  if (lane == 63) wsum[w] = x;
  __syncthreads();
  if (w == 0) {
    int s = (lane < 16) ? wsum[lane] : 0;
    #pragma unroll
    for (int d = 1; d < 16; d <<= 1) { int y = __shfl_up(s, d, 64); if (lane >= d) s += y; }
    if (lane < 16) wsum[lane] = s;
  }
  __syncthreads();
  int add = (w > 0) ? wsum[w - 1] : 0;
  x += add;
  if (gi < n) offs[gi + 1] = x;
  if (t == 1023) bsums[blockIdx.x] = x;
}

__global__ __launch_bounds__(64) void scan_bsums_kernel(
    const int* __restrict__ bsums, int nb, int* __restrict__ boff) {
  int l = threadIdx.x;
  int v = (l < nb) ? bsums[l] : 0;
  int x = v;
  #pragma unroll
  for (int d = 1; d < 64; d <<= 1) { int y = __shfl_up(x, d, 64); if (l >= d) x += y; }
  if (l < nb) boff[l] = x - v;   // exclusive
}

__global__ void scan_add_kernel(int* __restrict__ offs, const int* __restrict__ boff, int n) {
  int i = blockIdx.x * 256 + threadIdx.x;
  if (i < n) offs[i + 1] += boff[i >> 10];
  if (i == 0) offs[0] = 0;
}

__global__ void scatter_kernel(const int* __restrict__ src, const int* __restrict__ dst, int E,
                               const int* __restrict__ offs, int* __restrict__ cursor,
                               int2* __restrict__ recs) {
  int e = blockIdx.x * 256 + threadIdx.x;
  if (e < E) {
    int d = dst[e];
    int p = offs[d] + atomicAdd(&cursor[d], 1);
    recs[p] = make_int2(src[e], e);
  }
}

// Wave-per-node accumulation of T_n[25][32] in LDS, streamed to global T chunk.
__global__ __launch_bounds__(512) void acc_kernel(
    const int2* __restrict__ recs, const int* __restrict__ offs,
    const float2* __restrict__ attr, const float* __restrict__ X,
    float* __restrict__ T, int c0, int nEnd) {
  __shared__ float Tld[8][800];
  int w = threadIdx.x >> 6;
  int lane = threadIdx.x & 63;
  int n = c0 + blockIdx.x * 8 + w;
  if (n >= nEnd) return;                    // no barriers in this kernel
  for (int j = lane; j < 800; j += 64) Tld[w][j] = 0.f;
  int beg = __builtin_amdgcn_readfirstlane(offs[n]);
  int end = __builtin_amdgcn_readfirstlane(offs[n + 1]);
  int i = lane & 31, h = lane >> 5;
  for (int e = beg; e < end; ++e) {
    int2 r = recs[e];
    int sN = __builtin_amdgcn_readfirstlane(r.x);
    int ei = __builtin_amdgcn_readfirstlane(r.y);
    float2 a = attr[ei];
    float v0 = a.x * 4.f, v1 = a.y * 4.f;
    float l0 = floorf(v0), l1 = floorf(v1);
    float f0 = v0 - l0, f1 = v1 - l1;
    int i00 = (int)l0; int i01 = min(i00 + 1, 4); i00 = min(i00, 4);
    int i10 = (int)l1; int i11 = min(i10 + 1, 4); i10 = min(i10, 4);
    float b1d = h ? f1 : (1.f - f1);        // dim-1 basis for s1 = h
    int   k1d = h ? i11 : i10;
    float xj = X[(size_t)sN * 32 + i];
    atomicAdd(&Tld[w][(i00 + 5 * k1d) * 32 + i], ((1.f - f0) * b1d) * xj);
    atomicAdd(&Tld[w][(i01 + 5 * k1d) * 32 + i], (f0 * b1d) * xj);
  }
  float4* Tg = (float4*)(T + (size_t)(n - c0) * 800);
  #pragma unroll
  for (int q = 0; q < 4; ++q) {
    int j4 = q * 64 + lane;
    if (j4 < 200) Tg[j4] = *(const float4*)&Tld[w][j4 * 4];
  }
}

// Tiled GEMM: out[64 x COUT] = T[64 x 800] @ W[800 x COUT], fused epilogue:
// acc /= max(deg,1); acc += X[64 x 32] @ root[32 x COUT]; + bias; relu; store.
template <int COUT>
__global__ __launch_bounds__(256) void gemm_kernel(
    const float* __restrict__ T, const float* __restrict__ W,
    const float* __restrict__ X, const float* __restrict__ root,
    const float* __restrict__ bias, const int* __restrict__ deg,
    float* __restrict__ H, int c0, int Nvalid) {
  constexpr int NB = COUT / 16;             // 2 (COUT=32) or 4 (COUT=64)
  __shared__ float As[32 * 68];             // [BK=32][64 + pad4], 16B-aligned cols
  __shared__ float Bs[32 * COUT];
  const int t = threadIdx.x;
  const int tm = t & 15, tn = t >> 4;
  const int mBase = blockIdx.x * 64;
  float acc[4][NB];
  #pragma unroll
  for (int a = 0; a < 4; ++a)
    #pragma unroll
    for (int b = 0; b < NB; ++b) acc[a][b] = 0.f;

  for (int k0 = 0; k0 < 800; k0 += 32) {
    #pragma unroll
    for (int q = 0; q < 2; ++q) {           // stage A transposed
      int idx = q * 256 + t;
      int row = idx >> 3, kq = idx & 7;
      float4 v = *(const float4*)&T[(size_t)(mBase + row) * 800 + k0 + kq * 4];
      As[(kq * 4 + 0) * 68 + row] = v.x;
      As[(kq * 4 + 1) * 68 + row] = v.y;
      As[(kq * 4 + 2) * 68 + row] = v.z;
      As[(kq * 4 + 3) * 68 + row] = v.w;
    }
    #pragma unroll
    for (int q = 0; q < (32 * COUT) / 1024; ++q) {  // stage B row-major
      int idx = q * 256 + t;
      *(float4*)&Bs[idx * 4] = *(const float4*)&W[k0 * COUT + idx * 4];
    }
    __syncthreads();
    #pragma unroll
    for (int kk = 0; kk < 32; ++kk) {
      float4 av = *(const float4*)&As[kk * 68 + tm * 4];
      float bv[NB];
      if constexpr (COUT == 32) {
        float2 b2 = *(const float2*)&Bs[kk * 32 + tn * 2];
        bv[0] = b2.x; bv[1] = b2.y;
      } else {
        float4 b4 = *(const float4*)&Bs[kk * 64 + tn * 4];
        bv[0] = b4.x; bv[1] = b4.y; bv[2] = b4.z; bv[3] = b4.w;
      }
      const float am[4] = {av.x, av.y, av.z, av.w};
      #pragma unroll
      for (int mi = 0; mi < 4; ++mi)
        #pragma unroll
        for (int nj = 0; nj < NB; ++nj)
          acc[mi][nj] = fmaf(am[mi], bv[nj], acc[mi][nj]);
    }
    __syncthreads();
  }
  // mean (deg) applies only to the aggregated part
  #pragma unroll
  for (int mi = 0; mi < 4; ++mi) {
    int m = c0 + mBase + tm * 4 + mi;
    float rd = 1.f / (float)max(deg[m], 1);
    #pragma unroll
    for (int nj = 0; nj < NB; ++nj) acc[mi][nj] *= rd;
  }
  // root phase: one BK=32 pass with A=X rows, B=root
  {
    #pragma unroll
    for (int q = 0; q < 2; ++q) {
      int idx = q * 256 + t;
      int row = idx >> 3, kq = idx & 7;
      int gr = min(c0 + mBase + row, Nvalid - 1);
      float4 v = *(const float4*)&X[(size_t)gr * 32 + kq * 4];
      As[(kq * 4 + 0) * 68 + row] = v.x;
      As[(kq * 4 + 1) * 68 + row] = v.y;
      As[(kq * 4 + 2) * 68 + row] = v.z;
      As[(kq * 4 + 3) * 68 + row] = v.w;
    }
    #pragma unroll
    for (int q = 0; q < (32 * COUT) / 1024; ++q) {
      int idx = q * 256 + t;
      *(float4*)&Bs[idx * 4] = *(const float4*)&root[idx * 4];
    }
    __syncthreads();
    #pragma unroll
    for (int kk = 0; kk < 32; ++kk) {
      float4 av = *(const float4*)&As[kk * 68 + tm * 4];
      float bv[NB];
      if constexpr (COUT == 32) {
        float2 b2 = *(const float2*)&Bs[kk * 32 + tn * 2];
        bv[0] = b2.x; bv[1] = b2.y;
      } else {
        float4 b4 = *(const float4*)&Bs[kk * 64 + tn * 4];
        bv[0] = b4.x; bv[1] = b4.y; bv[2] = b4.z; bv[3] = b4.w;
      }
      const float am[4] = {av.x, av.y, av.z, av.w};
      #pragma unroll
      for (int mi = 0; mi < 4; ++mi)
        #pragma unroll
        for (int nj = 0; nj < NB; ++nj)
          acc[mi][nj] = fmaf(am[mi], bv[nj], acc[mi][nj]);
    }
  }
  float bv[NB];
  #pragma unroll
  for (int nj = 0; nj < NB; ++nj) bv[nj] = bias[tn * NB + nj];
  #pragma unroll
  for (int mi = 0; mi < 4; ++mi) {
    int m = c0 + mBase + tm * 4 + mi;
    if (m < Nvalid) {
      if constexpr (COUT == 32) {
        float2 o;
        o.x = fmaxf(acc[mi][0] + bv[0], 0.f);
        o.y = fmaxf(acc[mi][1] + bv[1], 0.f);
        *(float2*)&H[(size_t)m * 32 + tn * 2] = o;
      } else {
        float4 o;
        o.x = fmaxf(acc[mi][0] + bv[0], 0.f);
        o.y = fmaxf(acc[mi][1] + bv[1], 0.f);
        o.z = fmaxf(acc[mi][2] + bv[2], 0.f);
        o.w = fmaxf(acc[mi][3] + bv[3], 0.f);
        *(float4*)&H[(size_t)m * 64 + tn * 4] = o;
      }
    }
  }
}

__global__ __launch_bounds__(256) void pool_kernel(
    const float* __restrict__ h2, const int* __restrict__ batch, int N,
    float* __restrict__ poolacc) {
  __shared__ float red[4][64];
  int g = blockIdx.x >> 2, part = blockIdx.x & 3;
  int lo = lowb(batch, N, g), hi = lowb(batch, N, g + 1);
  int len = hi - lo;
  int b0 = lo + (int)(((long long)len * part) / 4);
  int b1 = lo + (int)(((long long)len * (part + 1)) / 4);
  int r = threadIdx.x >> 6, o = threadIdx.x & 63;
  float s = 0.f;
  for (int row = b0 + r; row < b1; row += 4) s += h2[(size_t)row * 64 + o];
  red[r][o] = s;
  __syncthreads();
  if (r == 0) {
    float v = red[0][o] + red[1][o] + red[2][o] + red[3][o];
    atomicAdd(&poolacc[g * 64 + o], v);
  }
}

__global__ __launch_bounds__(64) void head_kernel(
    const float* __restrict__ poolacc, const int* __restrict__ batch, int N,
    const float* __restrict__ w1, const float* __restrict__ b1,
    const float* __restrict__ w2, const float* __restrict__ b2,
    const float* __restrict__ w3, const float* __restrict__ b3,
    float* __restrict__ out) {
  __shared__ float gb[64];
  __shared__ float lg[10];
  int g = blockIdx.x, o = threadIdx.x;
  int lo = lowb(batch, N, g), hi = lowb(batch, N, g + 1);
  float cnt = fmaxf((float)(hi - lo), 1.f);
  float gv = poolacc[g * 64 + o] / cnt;
  gb[o] = gv;
  __syncthreads();
  float tacc = b1[o];
  for (int i = 0; i < 64; ++i) tacc = fmaf(gb[i], w1[i * 64 + o], tacc);
  gv = gv * (1.f / (1.f + expf(-tacc)));
  __syncthreads(); gb[o] = gv; __syncthreads();
  tacc = b2[o];
  for (int i = 0; i < 64; ++i) tacc = fmaf(gb[i], w2[i * 64 + o], tacc);
  gv = gv * (1.f / (1.f + expf(-tacc)));
  __syncthreads(); gb[o] = gv; __syncthreads();
  if (o < 10) {
    float l = b3[o];
    for (int i = 0; i < 64; ++i) l = fmaf(gb[i], w3[i * 10 + o], l);
    lg[o] = l;
  }
  __syncthreads();
  if (o < 10) {
    float m = lg[0];
    #pragma unroll
    for (int c = 1; c < 10; ++c) m = fmaxf(m, lg[c]);
    float s = 0.f;
    #pragma unroll
    for (int c = 0; c < 10; ++c) s += expf(lg[c] - m);
    out[g * 10 + o] = lg[o] - m - logf(s);
  }
}

extern "C" void kernel_launch(void* const* d_in, const int* in_sizes, int n_in,
                              void* d_out, int out_size, void* d_ws, size_t ws_size,
                              hipStream_t stream) {
  const float* x     = (const float*)d_in[0];
  const int*   ei    = (const int*)d_in[1];
  const float* eattr = (const float*)d_in[2];
  const int*   batch = (const int*)d_in[3];
  const float* W1    = (const float*)d_in[4];
  const float* root1 = (const float*)d_in[5];
  const float* b1    = (const float*)d_in[6];
  const float* W2    = (const float*)d_in[7];
  const float* root2 = (const float*)d_in[8];
  const float* b2    = (const float*)d_in[9];
  const float* l1w   = (const float*)d_in[10];
  const float* l1b   = (const float*)d_in[11];
  const float* l2w   = (const float*)d_in[12];
  const float* l2b   = (const float*)d_in[13];
  const float* l3w   = (const float*)d_in[14];
  const float* l3b   = (const float*)d_in[15];
  float* out = (float*)d_out;

  const int N = in_sizes[0] / 32;
  const int E = in_sizes[1] / 2;
  const int Npad = (N + 63) & ~63;

  char* base = (char*)d_ws;
  size_t off = 0;
  auto walloc = [&](size_t bytes) -> void* {
    off = (off + 255) & ~(size_t)255;
    void* p = base + off;
    off += bytes;
    return p;
  };
  int*   deg     = (int*)walloc((size_t)Npad * 4);
  int*   offs    = (int*)walloc((size_t)(N + 1) * 4);
  int*   cursor  = (int*)walloc((size_t)N * 4);
  int*   bsums   = (int*)walloc(64 * 4);
  int*   boff    = (int*)walloc(64 * 4);
  float* poolacc = (float*)walloc(64 * 64 * 4);
  float* h1      = (float*)walloc((size_t)N * 32 * 4);
  float* h2      = (float*)walloc((size_t)N * 64 * 4);
  int2*  recs    = (int2*)walloc((size_t)E * 8);
  off = (off + 255) & ~(size_t)255;
  size_t remain = (ws_size > off) ? (ws_size - off) : 0;
  int chunkRows = (int)(remain / (800 * 4));
  chunkRows &= ~63;
  if (chunkRows > 12800) chunkRows = 12800;
  if (chunkRows > Npad) chunkRows = Npad;
  if (chunkRows < 64) return;               // insufficient workspace
  float* T = (float*)(base + off);

  const int* srcA = ei;
  const int* dstA = ei + E;

  hipMemsetAsync(deg, 0, (size_t)Npad * 4, stream);
  hipMemsetAsync(cursor, 0, (size_t)N * 4, stream);
  hipMemsetAsync(poolacc, 0, 64 * 64 * 4, stream);

  hist_kernel<<<(E + 255) / 256, 256, 0, stream>>>(dstA, E, deg);
  int nb = (N + 1023) / 1024;
  scan_block_kernel<<<nb, 1024, 0, stream>>>(deg, N, offs, bsums);
  scan_bsums_kernel<<<1, 64, 0, stream>>>(bsums, nb, boff);
  scan_add_kernel<<<(N + 255) / 256, 256, 0, stream>>>(offs, boff, N);
  scatter_kernel<<<(E + 255) / 256, 256, 0, stream>>>(srcA, dstA, E, offs, cursor, recs);

  for (int layer = 0; layer < 2; ++layer) {
    const float* Xin = layer ? h1 : x;
    const float* Wl  = layer ? W2 : W1;
    const float* rl  = layer ? root2 : root1;
    const float* bl  = layer ? b2 : b1;
    float* Hout      = layer ? h2 : h1;
    for (int c0 = 0; c0 < N; c0 += chunkRows) {
      int cn = (chunkRows < N - c0) ? chunkRows : (N - c0);
      int accBlocks = (cn + 7) / 8;
      acc_kernel<<<accBlocks, 512, 0, stream>>>(recs, offs, (const float2*)eattr,
                                                Xin, T, c0, c0 + cn);
      int tiles = (cn + 63) / 64;
      if (layer == 0)
        gemm_kernel<32><<<tiles, 256, 0, stream>>>(T, Wl, Xin, rl, bl, deg, Hout, c0, N);
      else
        gemm_kernel<64><<<tiles, 256, 0, stream>>>(T, Wl, Xin, rl, bl, deg, Hout, c0, N);
    }
  }
  pool_kernel<<<256, 256, 0, stream>>>(h2, batch, N, poolacc);
  head_kernel<<<64, 64, 0, stream>>>(poolacc, batch, N,
                                     l1w, l1b, l2w, l2b, l3w, l3b, out);
}